// Round 4
// baseline (59.776 us; speedup 1.0000x reference)
//
#include <hip/hip_runtime.h>
#include <hip/hip_bf16.h>

#define N 8192
#define D 256
#define SP2 4
#define CPB (N / SP2)          // 2048 cols per block
#define NCH 16                 // 16 full-K chunks of 128 cols

typedef __bf16 bf16x8 __attribute__((ext_vector_type(8)));
typedef float f32x16 __attribute__((ext_vector_type(16)));

static __device__ __forceinline__ unsigned short f2bf(float x) {
    union { float f; unsigned int u; } c; c.f = x;
    unsigned int r = (c.u + 0x7fffu + ((c.u >> 16) & 1u)) >> 16;
    return (unsigned short)r;
}

static __device__ __forceinline__ void gll16(const void* g, void* l) {
    __builtin_amdgcn_global_load_lds(
        (const __attribute__((address_space(1))) void*)g,
        (__attribute__((address_space(3))) void*)l, 16, 0, 0);
}

#define WAIT_VM8  asm volatile("s_waitcnt vmcnt(8)" ::: "memory")
#define WAIT_VM0  asm volatile("s_waitcnt vmcnt(0)" ::: "memory")
#define WAIT_LG0  asm volatile("s_waitcnt lgkmcnt(0)" ::: "memory")
#define SBAR      __builtin_amdgcn_s_barrier()
#define SCHED0    __builtin_amdgcn_sched_barrier(0)

// ---------- kernel 1: norms + exact fp32 diag + normalized bf16 copies ----------
// A: linear layout (consumed into registers).  B: full-row 32-chunk XOR swizzle.
__global__ __launch_bounds__(256) void conv_k(const float* __restrict__ o1,
                                              const float* __restrict__ o2,
                                              unsigned char* __restrict__ a_bf,
                                              unsigned char* __restrict__ b_bf,
                                              float* __restrict__ diag) {
    const int wid = threadIdx.x >> 6, lane = threadIdx.x & 63;
    const int r = blockIdx.x * 4 + wid;
    const float4* p1 = (const float4*)(o1 + (size_t)r * D);
    const float4* p2 = (const float4*)(o2 + (size_t)r * D);
    float4 v1 = p1[lane], v2 = p2[lane];
    float s1 = v1.x*v1.x + v1.y*v1.y + v1.z*v1.z + v1.w*v1.w;
    float s2 = v2.x*v2.x + v2.y*v2.y + v2.z*v2.z + v2.w*v2.w;
    float sd = v1.x*v2.x + v1.y*v2.y + v1.z*v2.z + v1.w*v2.w;
    #pragma unroll
    for (int m = 1; m < 64; m <<= 1) {
        s1 += __shfl_xor(s1, m);
        s2 += __shfl_xor(s2, m);
        sd += __shfl_xor(sd, m);
    }
    float i1 = 1.0f / sqrtf(s1);
    float i2 = 1.0f / sqrtf(s2);
    if (lane == 0) diag[r] = sd * i1 * i2;

    // A: linear
    {
        unsigned int lo = (unsigned int)f2bf(v1.x * i1) | ((unsigned int)f2bf(v1.y * i1) << 16);
        unsigned int hi = (unsigned int)f2bf(v1.z * i1) | ((unsigned int)f2bf(v1.w * i1) << 16);
        uint2 q; q.x = lo; q.y = hi;
        *(uint2*)(a_bf + (size_t)r * 512 + lane * 8) = q;
    }
    // B: 512B rows, 32 chunks of 16B, chunk c -> c ^ (r&31)
    {
        unsigned int lo = (unsigned int)f2bf(v2.x * i2) | ((unsigned int)f2bf(v2.y * i2) << 16);
        unsigned int hi = (unsigned int)f2bf(v2.z * i2) | ((unsigned int)f2bf(v2.w * i2) << 16);
        int c  = lane >> 1;
        int cs = c ^ (r & 31);
        uint2 q; q.x = lo; q.y = hi;
        *(uint2*)(b_bf + (size_t)r * 512 + cs * 16 + (lane & 1) * 8) = q;
    }
}

// ---------- kernel 2: A-in-registers pipelined bf16 GEMM + row-wise sum(exp) ----------
// stage full-K chunk T (128 cols x 512B) into BBUF
#define STAGE_B(T, BBUF)                                                        \
    {                                                                           \
        const int c0_ = (T) * 128;                                              \
        _Pragma("unroll")                                                       \
        for (int it = 0; it < 8; ++it) {                                        \
            int x_ = it * 8192 + tid * 16;                                      \
            gll16(bG + (size_t)(c0_ + (x_ >> 9)) * 512 + (x_ & 511),            \
                  (BBUF) + x_);                                                 \
        }                                                                       \
    }

#define COMPUTE(BBUF)                                                           \
    {                                                                           \
        _Pragma("unroll")                                                       \
        for (int ksi = 0; ksi < 16; ++ksi) {                                    \
            const int cs_ = ((ksi * 2 + lhi)) ^ l31;                            \
            bf16x8 bb = *(const bf16x8*)((BBUF) + (wc * 32 + l31) * 512 + cs_ * 16); \
            acc0 = __builtin_amdgcn_mfma_f32_32x32x16_bf16(af0[ksi], bb, acc0, 0, 0, 0); \
            acc1 = __builtin_amdgcn_mfma_f32_32x32x16_bf16(af1[ksi], bb, acc1, 0, 0, 0); \
        }                                                                       \
    }

__global__ __launch_bounds__(512, 1) void gemm4(const unsigned char* __restrict__ a_bf,
                                                const unsigned char* __restrict__ b_bf,
                                                float* __restrict__ s_part) {
    __shared__ __align__(16) unsigned char b_lds0[128 * 512];   // 64 KB
    __shared__ __align__(16) unsigned char b_lds1[128 * 512];   // 64 KB
    __shared__ float red[4][128];

    const int tid = threadIdx.x;
    const int lane = tid & 63, wid = tid >> 6;
    const int wr = wid >> 2, wc = wid & 3;          // 2 x 4 wave grid
    const int l31 = lane & 31, lhi = lane >> 5;

    // XCD-aware decode: 2 XCDs per sp-panel, 32 rb-blocks each
    const int bid = blockIdx.x;
    const int sp = (bid & 7) >> 1;
    const int rb = (bid >> 3) + 32 * (bid & 1);

    const unsigned char* aG = a_bf + (size_t)rb * (128 * 512);
    const unsigned char* bG = b_bf + (size_t)sp * ((size_t)CPB * 512);

    // prologue: A fragments -> registers (reused for all 16 phases)
    bf16x8 af0[16], af1[16];
    {
        const int row0 = wr * 64 + l31;
        const int row1 = wr * 64 + 32 + l31;
        #pragma unroll
        for (int ksi = 0; ksi < 16; ++ksi) {
            af0[ksi] = *(const bf16x8*)(aG + (size_t)row0 * 512 + ksi * 32 + lhi * 16);
            af1[ksi] = *(const bf16x8*)(aG + (size_t)row1 * 512 + ksi * 32 + lhi * 16);
        }
    }
    STAGE_B(0, b_lds0);

    float srow0[16], srow1[16];
    #pragma unroll
    for (int r = 0; r < 16; ++r) { srow0[r] = 0.f; srow1[r] = 0.f; }

    f32x16 acc0, acc1;

    #pragma unroll 1
    for (int p = 0; p < NCH; ++p) {
        unsigned char* cur = (p & 1) ? b_lds1 : b_lds0;
        unsigned char* nxt = (p & 1) ? b_lds0 : b_lds1;
        if (p < NCH - 1) {
            STAGE_B(p + 1, nxt);
            WAIT_VM8;                 // chunk p (and A-frags) landed
        } else {
            WAIT_VM0;
        }
        SCHED0;
        SBAR;                         // chunk p visible to all waves

        #pragma unroll
        for (int r = 0; r < 16; ++r) { acc0[r] = 0.f; acc1[r] = 0.f; }
        __builtin_amdgcn_s_setprio(1);
        COMPUTE(cur);
        __builtin_amdgcn_s_setprio(0);
        #pragma unroll
        for (int r = 0; r < 16; ++r) {
            srow0[r] += __expf(acc0[r]);
            srow1[r] += __expf(acc1[r]);
        }
        WAIT_LG0;                     // my ds_reads of cur complete
        SCHED0;
        SBAR;                         // cur released for overwrite at p+2
    }

    // reduce across the 32 column-lanes (C layout: col = lane&31)
    #pragma unroll
    for (int r = 0; r < 16; ++r) {
        float v0 = srow0[r], v1 = srow1[r];
        #pragma unroll
        for (int m = 1; m < 32; m <<= 1) {
            v0 += __shfl_xor(v0, m);
            v1 += __shfl_xor(v1, m);
        }
        srow0[r] = v0; srow1[r] = v1;
    }
    if (l31 == 0) {
        #pragma unroll
        for (int r = 0; r < 16; ++r) {
            int rl = wr * 64 + 4 * lhi + (r & 3) + 8 * (r >> 2);
            red[wc][rl]      = srow0[r];
            red[wc][rl + 32] = srow1[r];
        }
    }
    __syncthreads();
    if (tid < 128) {
        float s = red[0][tid] + red[1][tid] + red[2][tid] + red[3][tid];
        s_part[(size_t)sp * N + rb * 128 + tid] = s;
    }
}

// ---------- kernel 3: per-row loss ----------
__global__ __launch_bounds__(128) void rowloss2(const float* __restrict__ s_part,
                                                const float* __restrict__ diag,
                                                float* __restrict__ partial) {
    const int t = threadIdx.x, rb = blockIdx.x;
    float s = 0.f;
    #pragma unroll
    for (int sp = 0; sp < SP2; ++sp)
        s += s_part[(size_t)sp * N + rb * 128 + t];
    float loss = logf(s) - diag[rb * 128 + t];
    #pragma unroll
    for (int m = 1; m < 64; m <<= 1) loss += __shfl_xor(loss, m);
    __shared__ float redl[2];
    if ((t & 63) == 0) redl[t >> 6] = loss;
    __syncthreads();
    if (t == 0) partial[rb] = redl[0] + redl[1];
}

// ---------- kernel 4: final mean ----------
__global__ __launch_bounds__(64) void final_k(const float* __restrict__ partial,
                                              float* __restrict__ out) {
    const int t = threadIdx.x;
    float v = partial[t];
    #pragma unroll
    for (int m = 1; m < 64; m <<= 1) v += __shfl_xor(v, m);
    if (t == 0) out[0] = v / (float)N;
}

extern "C" void kernel_launch(void* const* d_in, const int* in_sizes, int n_in,
                              void* d_out, int out_size, void* d_ws, size_t ws_size,
                              hipStream_t stream) {
    const float* o1 = (const float*)d_in[0];
    const float* o2 = (const float*)d_in[1];

    unsigned char* w = (unsigned char*)d_ws;
    unsigned char* a_bf = w;                                   // 4 MB
    unsigned char* b_bf = w + (size_t)4 * 1024 * 1024;         // 4 MB
    float* diag    = (float*)(w + (size_t)8 * 1024 * 1024);    // 32 KB
    float* s_part  = diag + N;                                 // 128 KB
    float* partial = s_part + (size_t)SP2 * N;                 // 256 B

    conv_k<<<N / 4, 256, 0, stream>>>(o1, o2, a_bf, b_bf, diag);
    gemm4<<<256, 512, 0, stream>>>(a_bf, b_bf, s_part);
    rowloss2<<<N / 128, 128, 0, stream>>>(s_part, diag, partial);
    final_k<<<1, 64, 0, stream>>>(partial, (float*)d_out);
}

// Round 5
// 57.244 us; speedup vs baseline: 1.0442x; 1.0442x over previous
//
#include <hip/hip_runtime.h>
#include <hip/hip_bf16.h>

#define N 8192
#define D 256
#define SP 8
#define NCHK 16                // 16 chunks of 64 cols = 1024 cols per block

typedef __bf16 bf16x8 __attribute__((ext_vector_type(8)));
typedef float f32x16 __attribute__((ext_vector_type(16)));

static __device__ __forceinline__ unsigned short f2bf(float x) {
    union { float f; unsigned int u; } c; c.f = x;
    unsigned int r = (c.u + 0x7fffu + ((c.u >> 16) & 1u)) >> 16;
    return (unsigned short)r;
}

static __device__ __forceinline__ void gll16(const void* g, void* l) {
    __builtin_amdgcn_global_load_lds(
        (const __attribute__((address_space(1))) void*)g,
        (__attribute__((address_space(3))) void*)l, 16, 0, 0);
}

#define WAIT_VM4  asm volatile("s_waitcnt vmcnt(4)" ::: "memory")
#define WAIT_VM0  asm volatile("s_waitcnt vmcnt(0)" ::: "memory")
#define WAIT_LG0  asm volatile("s_waitcnt lgkmcnt(0)" ::: "memory")
#define SBAR      __builtin_amdgcn_s_barrier()
#define SCHED0    __builtin_amdgcn_sched_barrier(0)

// ---------- kernel 1: norms + exact fp32 diag + normalized bf16 copies ----------
// A: linear layout (consumed into register/AGPR fragments).
// B: 512B rows, 32 chunks of 16B, chunk c -> c ^ (r&31) XOR pre-swizzle.
__global__ __launch_bounds__(256) void conv_k(const float* __restrict__ o1,
                                              const float* __restrict__ o2,
                                              unsigned char* __restrict__ a_bf,
                                              unsigned char* __restrict__ b_bf,
                                              float* __restrict__ diag) {
    const int wid = threadIdx.x >> 6, lane = threadIdx.x & 63;
    const int r = blockIdx.x * 4 + wid;
    const float4* p1 = (const float4*)(o1 + (size_t)r * D);
    const float4* p2 = (const float4*)(o2 + (size_t)r * D);
    float4 v1 = p1[lane], v2 = p2[lane];
    float s1 = v1.x*v1.x + v1.y*v1.y + v1.z*v1.z + v1.w*v1.w;
    float s2 = v2.x*v2.x + v2.y*v2.y + v2.z*v2.z + v2.w*v2.w;
    float sd = v1.x*v2.x + v1.y*v2.y + v1.z*v2.z + v1.w*v2.w;
    #pragma unroll
    for (int m = 1; m < 64; m <<= 1) {
        s1 += __shfl_xor(s1, m);
        s2 += __shfl_xor(s2, m);
        sd += __shfl_xor(sd, m);
    }
    float i1 = 1.0f / sqrtf(s1);
    float i2 = 1.0f / sqrtf(s2);
    if (lane == 0) diag[r] = sd * i1 * i2;

    {   // A linear
        unsigned int lo = (unsigned int)f2bf(v1.x * i1) | ((unsigned int)f2bf(v1.y * i1) << 16);
        unsigned int hi = (unsigned int)f2bf(v1.z * i1) | ((unsigned int)f2bf(v1.w * i1) << 16);
        uint2 q; q.x = lo; q.y = hi;
        *(uint2*)(a_bf + (size_t)r * 512 + lane * 8) = q;
    }
    {   // B swizzled
        unsigned int lo = (unsigned int)f2bf(v2.x * i2) | ((unsigned int)f2bf(v2.y * i2) << 16);
        unsigned int hi = (unsigned int)f2bf(v2.z * i2) | ((unsigned int)f2bf(v2.w * i2) << 16);
        int c  = lane >> 1;
        int cs = c ^ (r & 31);
        uint2 q; q.x = lo; q.y = hi;
        *(uint2*)(b_bf + (size_t)r * 512 + cs * 16 + (lane & 1) * 8) = q;
    }
}

// ---------- kernel 2: triple-buffered counted-vmcnt GEMM + row-wise sum(exp) ----------
__global__ __launch_bounds__(512, 2) void gemm5(const unsigned char* __restrict__ a_bf,
                                                const unsigned char* __restrict__ b_bf,
                                                float* __restrict__ s_part) {
    __shared__ __align__(16) unsigned char bls[3][64 * 512];   // 96 KB
    __shared__ float red[2][256];                              // 2 KB

    const int tid = threadIdx.x;
    const int lane = tid & 63, wid = tid >> 6;
    const int wr = wid >> 1, wc = wid & 1;          // 4 row-waves x 2 col-waves
    const int l31 = lane & 31, lhi = lane >> 5;
    const int bid = blockIdx.x;
    const int sp = bid & 7, rb = bid >> 3;          // per-XCD single B panel

    const unsigned char* aG = a_bf + (size_t)rb * (256 * 512);
    const unsigned char* bG = b_bf + (size_t)sp * ((size_t)1024 * 512);

    // A fragments: 64 rows per wave, full K (compiler may place in AGPRs)
    bf16x8 af0[16], af1[16];
    #pragma unroll
    for (int k = 0; k < 16; ++k) {
        af0[k] = *(const bf16x8*)(aG + (size_t)(wr * 64 + l31) * 512 + k * 32 + lhi * 16);
        af1[k] = *(const bf16x8*)(aG + (size_t)(wr * 64 + 32 + l31) * 512 + k * 32 + lhi * 16);
    }
    // prologue: stage chunks 0,1 (each 64 cols x 512B = 32 KB, linear copy)
    #pragma unroll
    for (int it = 0; it < 4; ++it) {
        int x = it * 8192 + tid * 16;
        gll16(bG + x, &bls[0][x]);
    }
    #pragma unroll
    for (int it = 0; it < 4; ++it) {
        int x = it * 8192 + tid * 16;
        gll16(bG + 32768 + x, &bls[1][x]);
    }

    float srow0[16], srow1[16];
    #pragma unroll
    for (int r = 0; r < 16; ++r) { srow0[r] = 0.f; srow1[r] = 0.f; }

    const unsigned char* cur = bls[0];
    const unsigned char* nx1 = bls[1];
    const unsigned char* stg = bls[2];

    #pragma unroll 1
    for (int p = 0; p < NCHK; ++p) {
        // ---- chunk boundary: my chunk-p loads landed; p+1's stay in flight ----
        if (p < NCHK - 1) { WAIT_VM4; } else { WAIT_VM0; }
        SCHED0;
        SBAR;   // all waves' chunk-p stages landed; all waves done reading p-1

        // stage chunk p+2 into buf[(p+2)%3]  (== buf p-1, released by SBAR)
        if (p < NCHK - 2) {
            const unsigned char* src = bG + (size_t)(p + 2) * 32768;
            #pragma unroll
            for (int it = 0; it < 4; ++it) {
                int x = it * 8192 + tid * 16;
                gll16(src + x, (unsigned char*)stg + x);
            }
        }

        f32x16 acc0, acc1;
        #pragma unroll
        for (int r = 0; r < 16; ++r) { acc0[r] = 0.f; acc1[r] = 0.f; }

        __builtin_amdgcn_s_setprio(1);
        #pragma unroll
        for (int ksi = 0; ksi < 16; ++ksi) {
            const int cs = (ksi * 2 + lhi) ^ l31;
            bf16x8 bb = *(const bf16x8*)(cur + (wc * 32 + l31) * 512 + cs * 16);
            acc0 = __builtin_amdgcn_mfma_f32_32x32x16_bf16(af0[ksi], bb, acc0, 0, 0, 0);
            acc1 = __builtin_amdgcn_mfma_f32_32x32x16_bf16(af1[ksi], bb, acc1, 0, 0, 0);
        }
        __builtin_amdgcn_s_setprio(0);
        WAIT_LG0;      // my reads of cur retired (release for p+3's stage)
        SCHED0;

        // cos bounded ~1: no running max needed
        #pragma unroll
        for (int r = 0; r < 16; ++r) {
            srow0[r] += __expf(acc0[r]);
            srow1[r] += __expf(acc1[r]);
        }

        const unsigned char* t = cur; cur = nx1; nx1 = stg; stg = t;
    }

    // reduce across the 32 column-lanes (C layout: col = lane&31)
    #pragma unroll
    for (int r = 0; r < 16; ++r) {
        float v0 = srow0[r], v1 = srow1[r];
        #pragma unroll
        for (int m = 1; m < 32; m <<= 1) {
            v0 += __shfl_xor(v0, m);
            v1 += __shfl_xor(v1, m);
        }
        srow0[r] = v0; srow1[r] = v1;
    }
    if (l31 == 0) {
        #pragma unroll
        for (int r = 0; r < 16; ++r) {
            int rl = wr * 64 + 4 * lhi + (r & 3) + 8 * (r >> 2);
            red[wc][rl]      = srow0[r];
            red[wc][rl + 32] = srow1[r];
        }
    }
    __syncthreads();
    if (tid < 256) {
        s_part[(size_t)sp * N + rb * 256 + tid] = red[0][tid] + red[1][tid];
    }
}

// ---------- kernel 3: per-row loss ----------
__global__ __launch_bounds__(128) void rowloss3(const float* __restrict__ s_part,
                                                const float* __restrict__ diag,
                                                float* __restrict__ partial) {
    const int t = threadIdx.x, rb = blockIdx.x;
    float s = 0.f;
    #pragma unroll
    for (int sp = 0; sp < SP; ++sp)
        s += s_part[(size_t)sp * N + rb * 128 + t];
    float loss = logf(s) - diag[rb * 128 + t];
    #pragma unroll
    for (int m = 1; m < 64; m <<= 1) loss += __shfl_xor(loss, m);
    __shared__ float redl[2];
    if ((t & 63) == 0) redl[t >> 6] = loss;
    __syncthreads();
    if (t == 0) partial[rb] = redl[0] + redl[1];
}

// ---------- kernel 4: final mean ----------
__global__ __launch_bounds__(64) void final_k(const float* __restrict__ partial,
                                              float* __restrict__ out) {
    const int t = threadIdx.x;
    float v = partial[t];
    #pragma unroll
    for (int m = 1; m < 64; m <<= 1) v += __shfl_xor(v, m);
    if (t == 0) out[0] = v / (float)N;
}

extern "C" void kernel_launch(void* const* d_in, const int* in_sizes, int n_in,
                              void* d_out, int out_size, void* d_ws, size_t ws_size,
                              hipStream_t stream) {
    const float* o1 = (const float*)d_in[0];
    const float* o2 = (const float*)d_in[1];

    unsigned char* w = (unsigned char*)d_ws;
    unsigned char* a_bf = w;                                   // 4 MB
    unsigned char* b_bf = w + (size_t)4 * 1024 * 1024;         // 4 MB
    float* diag    = (float*)(w + (size_t)8 * 1024 * 1024);    // 32 KB
    float* s_part  = diag + N;                                 // SP*N = 256 KB
    float* partial = s_part + (size_t)SP * N;                  // 256 B

    conv_k<<<N / 4, 256, 0, stream>>>(o1, o2, a_bf, b_bf, diag);
    gemm5<<<256, 512, 0, stream>>>(a_bf, b_bf, s_part);
    rowloss3<<<N / 128, 128, 0, stream>>>(s_part, diag, partial);
    final_k<<<1, 64, 0, stream>>>(partial, (float*)d_out);
}

// Round 7
// 50.896 us; speedup vs baseline: 1.1745x; 1.1247x over previous
//
#include <hip/hip_runtime.h>
#include <hip/hip_bf16.h>

#define N 8192
#define D 256
#define SP 8
#define NCHK 16                // 16 chunks of 64 cols = 1024 cols per block

typedef __bf16 bf16x8 __attribute__((ext_vector_type(8)));
typedef float f32x4 __attribute__((ext_vector_type(4)));

static __device__ __forceinline__ unsigned short f2bf(float x) {
    union { float f; unsigned int u; } c; c.f = x;
    unsigned int r = (c.u + 0x7fffu + ((c.u >> 16) & 1u)) >> 16;
    return (unsigned short)r;
}

static __device__ __forceinline__ void gll16(const void* g, void* l) {
    __builtin_amdgcn_global_load_lds(
        (const __attribute__((address_space(1))) void*)g,
        (__attribute__((address_space(3))) void*)l, 16, 0, 0);
}

#define WAIT_VM4  asm volatile("s_waitcnt vmcnt(4)" ::: "memory")
#define WAIT_VM0  asm volatile("s_waitcnt vmcnt(0)" ::: "memory")
#define WAIT_LG0  asm volatile("s_waitcnt lgkmcnt(0)" ::: "memory")
#define SBAR      __builtin_amdgcn_s_barrier()
#define SCHED0    __builtin_amdgcn_sched_barrier(0)

// ---------- kernel 1: norms + exact fp32 diag + normalized bf16 copies ----------
// A: linear layout (consumed into register fragments).
// B: 512B rows, 32 chunks of 16B, chunk c -> c ^ (r&31) XOR pre-swizzle.
__global__ __launch_bounds__(256) void conv_k(const float* __restrict__ o1,
                                              const float* __restrict__ o2,
                                              unsigned char* __restrict__ a_bf,
                                              unsigned char* __restrict__ b_bf,
                                              float* __restrict__ diag) {
    const int wid = threadIdx.x >> 6, lane = threadIdx.x & 63;
    const int r = blockIdx.x * 4 + wid;
    const float4* p1 = (const float4*)(o1 + (size_t)r * D);
    const float4* p2 = (const float4*)(o2 + (size_t)r * D);
    float4 v1 = p1[lane], v2 = p2[lane];
    float s1 = v1.x*v1.x + v1.y*v1.y + v1.z*v1.z + v1.w*v1.w;
    float s2 = v2.x*v2.x + v2.y*v2.y + v2.z*v2.z + v2.w*v2.w;
    float sd = v1.x*v2.x + v1.y*v2.y + v1.z*v2.z + v1.w*v2.w;
    #pragma unroll
    for (int m = 1; m < 64; m <<= 1) {
        s1 += __shfl_xor(s1, m);
        s2 += __shfl_xor(s2, m);
        sd += __shfl_xor(sd, m);
    }
    float i1 = 1.0f / sqrtf(s1);
    float i2 = 1.0f / sqrtf(s2);
    if (lane == 0) diag[r] = sd * i1 * i2;

    {   // A linear
        unsigned int lo = (unsigned int)f2bf(v1.x * i1) | ((unsigned int)f2bf(v1.y * i1) << 16);
        unsigned int hi = (unsigned int)f2bf(v1.z * i1) | ((unsigned int)f2bf(v1.w * i1) << 16);
        uint2 q; q.x = lo; q.y = hi;
        *(uint2*)(a_bf + (size_t)r * 512 + lane * 8) = q;
    }
    {   // B swizzled
        unsigned int lo = (unsigned int)f2bf(v2.x * i2) | ((unsigned int)f2bf(v2.y * i2) << 16);
        unsigned int hi = (unsigned int)f2bf(v2.z * i2) | ((unsigned int)f2bf(v2.w * i2) << 16);
        int c  = lane >> 1;
        int cs = c ^ (r & 31);
        uint2 q; q.x = lo; q.y = hi;
        *(uint2*)(b_bf + (size_t)r * 512 + cs * 16 + (lane & 1) * 8) = q;
    }
}

// ---------- kernel 2: 16x16x32 many-chain GEMM + row-wise sum(exp) ----------
// block: 256 rows x 1024 cols; 8 waves, wave = 32 rows x 64 cols (whole chunk width)
// per wave: acc[2][4] (8 independent MFMA chains), af[2][8] in registers
__global__ __launch_bounds__(512, 2) void gemm6(const unsigned char* __restrict__ a_bf,
                                                const unsigned char* __restrict__ b_bf,
                                                float* __restrict__ s_part) {
    __shared__ __align__(16) unsigned char bls[3][64 * 512];   // 96 KB

    const int tid = threadIdx.x;
    const int lane = tid & 63, wid = tid >> 6;      // wid = row-wave 0..7
    const int l15 = lane & 15, lk = lane >> 4;      // lk = k-group 0..3
    const int bid = blockIdx.x;
    const int sp = bid & 7, rb = bid >> 3;          // per-XCD single B panel

    const unsigned char* aG = a_bf + (size_t)rb * (256 * 512);
    const unsigned char* bG = b_bf + (size_t)sp * ((size_t)1024 * 512);

    // A fragments in registers: rows wid*32 + mr*16 + l15, k-bytes ks*64 + lk*16
    bf16x8 af[2][8];
    #pragma unroll
    for (int mr = 0; mr < 2; ++mr)
        #pragma unroll
        for (int ks = 0; ks < 8; ++ks)
            af[mr][ks] = *(const bf16x8*)(aG + (size_t)(wid * 32 + mr * 16 + l15) * 512
                                             + ks * 64 + lk * 16);

    // prologue: stage chunks 0,1 (each 64 cols x 512B = 32 KB, linear copy)
    #pragma unroll
    for (int it = 0; it < 4; ++it) {
        int x = it * 8192 + tid * 16;
        gll16(bG + x, &bls[0][x]);
    }
    #pragma unroll
    for (int it = 0; it < 4; ++it) {
        int x = it * 8192 + tid * 16;
        gll16(bG + 32768 + x, &bls[1][x]);
    }

    float srow[2][4];
    #pragma unroll
    for (int mr = 0; mr < 2; ++mr)
        #pragma unroll
        for (int rg = 0; rg < 4; ++rg) srow[mr][rg] = 0.f;

    const unsigned char* cur = bls[0];
    const unsigned char* nx1 = bls[1];
    const unsigned char* stg = bls[2];

    #pragma unroll 1
    for (int p = 0; p < NCHK; ++p) {
        if (p < NCHK - 1) { WAIT_VM4; } else { WAIT_VM0; }
        SCHED0;
        SBAR;   // chunk p staged & visible; all waves done reading p-1

        if (p < NCHK - 2) {
            const unsigned char* src = bG + (size_t)(p + 2) * 32768;
            #pragma unroll
            for (int it = 0; it < 4; ++it) {
                int x = it * 8192 + tid * 16;
                gll16(src + x, (unsigned char*)stg + x);
            }
        }

        f32x4 acc[2][4];
        #pragma unroll
        for (int mr = 0; mr < 2; ++mr)
            #pragma unroll
            for (int nc = 0; nc < 4; ++nc)
                acc[mr][nc] = (f32x4){0.f, 0.f, 0.f, 0.f};

        __builtin_amdgcn_s_setprio(1);
        #pragma unroll
        for (int ks = 0; ks < 8; ++ks) {
            bf16x8 bb[4];
            #pragma unroll
            for (int nc = 0; nc < 4; ++nc) {
                const int col = nc * 16 + l15;
                const int cs = (ks * 4 + lk) ^ (col & 31);   // swizzle key is r&31
                bb[nc] = *(const bf16x8*)(cur + col * 512 + cs * 16);
            }
            #pragma unroll
            for (int nc = 0; nc < 4; ++nc)
                #pragma unroll
                for (int mr = 0; mr < 2; ++mr)
                    acc[mr][nc] = __builtin_amdgcn_mfma_f32_16x16x32_bf16(
                        af[mr][ks], bb[nc], acc[mr][nc], 0, 0, 0);
        }
        __builtin_amdgcn_s_setprio(0);
        WAIT_LG0;      // my reads of cur retired (release for later stages)
        SCHED0;

        // cos bounded ~1: no running max needed
        #pragma unroll
        for (int mr = 0; mr < 2; ++mr)
            #pragma unroll
            for (int rg = 0; rg < 4; ++rg)
                srow[mr][rg] += __expf(acc[mr][0][rg]) + __expf(acc[mr][1][rg])
                              + __expf(acc[mr][2][rg]) + __expf(acc[mr][3][rg]);

        const unsigned char* t = cur; cur = nx1; nx1 = stg; stg = t;
    }

    // reduce across the 16 column-lanes (C layout: col = lane&15, row = lk*4+rg)
    #pragma unroll
    for (int mr = 0; mr < 2; ++mr)
        #pragma unroll
        for (int rg = 0; rg < 4; ++rg) {
            float v = srow[mr][rg];
            v += __shfl_xor(v, 1);
            v += __shfl_xor(v, 2);
            v += __shfl_xor(v, 4);
            v += __shfl_xor(v, 8);
            srow[mr][rg] = v;
        }
    if (l15 == 0) {
        #pragma unroll
        for (int mr = 0; mr < 2; ++mr)
            #pragma unroll
            for (int rg = 0; rg < 4; ++rg) {
                int row = wid * 32 + mr * 16 + lk * 4 + rg;
                s_part[(size_t)sp * N + rb * 256 + row] = srow[mr][rg];
            }
    }
}

// ---------- kernel 3: per-row loss ----------
__global__ __launch_bounds__(128) void rowloss3(const float* __restrict__ s_part,
                                                const float* __restrict__ diag,
                                                float* __restrict__ partial) {
    const int t = threadIdx.x, rb = blockIdx.x;
    float s = 0.f;
    #pragma unroll
    for (int sp = 0; sp < SP; ++sp)
        s += s_part[(size_t)sp * N + rb * 128 + t];
    float loss = logf(s) - diag[rb * 128 + t];
    #pragma unroll
    for (int m = 1; m < 64; m <<= 1) loss += __shfl_xor(loss, m);
    __shared__ float redl[2];
    if ((t & 63) == 0) redl[t >> 6] = loss;
    __syncthreads();
    if (t == 0) partial[rb] = redl[0] + redl[1];
}

// ---------- kernel 4: final mean ----------
__global__ __launch_bounds__(64) void final_k(const float* __restrict__ partial,
                                              float* __restrict__ out) {
    const int t = threadIdx.x;
    float v = partial[t];
    #pragma unroll
    for (int m = 1; m < 64; m <<= 1) v += __shfl_xor(v, m);
    if (t == 0) out[0] = v / (float)N;
}

extern "C" void kernel_launch(void* const* d_in, const int* in_sizes, int n_in,
                              void* d_out, int out_size, void* d_ws, size_t ws_size,
                              hipStream_t stream) {
    const float* o1 = (const float*)d_in[0];
    const float* o2 = (const float*)d_in[1];

    unsigned char* w = (unsigned char*)d_ws;
    unsigned char* a_bf = w;                                   // 4 MB
    unsigned char* b_bf = w + (size_t)4 * 1024 * 1024;         // 4 MB
    float* diag    = (float*)(w + (size_t)8 * 1024 * 1024);    // 32 KB
    float* s_part  = diag + N;                                 // SP*N = 256 KB
    float* partial = s_part + (size_t)SP * N;                  // 256 B

    conv_k<<<N / 4, 256, 0, stream>>>(o1, o2, a_bf, b_bf, diag);
    gemm6<<<256, 512, 0, stream>>>(a_bf, b_bf, s_part);
    rowloss3<<<N / 128, 128, 0, stream>>>(s_part, diag, partial);
    final_k<<<1, 64, 0, stream>>>(partial, (float*)d_out);
}